// Round 1
// baseline (139.307 us; speedup 1.0000x reference)
//
#include <hip/hip_runtime.h>
#include <hip/hip_fp16.h>

#define B_    4
#define C_    192
#define N_    8192
#define K_    16
#define O_    192
#define TWOC_ 384

typedef __attribute__((ext_vector_type(8))) _Float16 half8;
typedef __attribute__((ext_vector_type(4))) _Float16 half4v;
typedef __attribute__((ext_vector_type(4))) float floatx4;

#define NINF ((_Float16)(-65504.0f))

// ---------------- K0: W fp32 -> fp16 ----------------
__global__ __launch_bounds__(256) void k_convert_w(const float* __restrict__ W,
                                                   unsigned short* __restrict__ Wb) {
    int i = blockIdx.x * 256 + threadIdx.x;
    if (i < O_ * TWOC_) {
        union { _Float16 h; unsigned short s; } v;
        v.h = (_Float16)W[i];
        Wb[i] = v.s;
    }
}

// ---------------- K1: x[B,C,N] fp32 -> xt[B,N,192] fp16 (compact) ----------------
__global__ __launch_bounds__(256) void k_transpose(const float* __restrict__ x,
                                                   unsigned short* __restrict__ xt) {
    __shared__ float tile[32][33];
    int bid  = blockIdx.x;               // 6144 blocks
    int xcd  = bid & 7;
    int b    = xcd >> 1;
    int half = xcd & 1;
    int slot = bid >> 3;                 // 0..767
    int ct   = slot >> 7;                // 0..5
    int nt   = half * 128 + (slot & 127);// 0..255
    int c0 = ct * 32, n0 = nt * 32;
    int tid = threadIdx.x;

    int cc  = tid >> 3;                  // 0..31
    int nn4 = (tid & 7) * 4;             // 0,4,..,28
    const float* xp = x + ((size_t)b * C_ + c0 + cc) * N_ + n0 + nn4;
    float4 v = *(const float4*)xp;
    tile[nn4 + 0][cc] = v.x;
    tile[nn4 + 1][cc] = v.y;
    tile[nn4 + 2][cc] = v.z;
    tile[nn4 + 3][cc] = v.w;
    __syncthreads();

#pragma unroll
    for (int i = 0; i < 2; i++) {
        int id  = i * 256 + tid;         // 0..511
        int row = id >> 4;               // 0..31
        int ch2 = id & 15;               // 0..15
        union { _Float16 h[2]; unsigned int u; } p;
        p.h[0] = (_Float16)tile[row][ch2 * 2];
        p.h[1] = (_Float16)tile[row][ch2 * 2 + 1];
        *(unsigned int*)(xt + ((size_t)b * N_ + n0 + row) * C_ + c0 + ch2 * 2) = p.u;
    }
}

// ---------------- K2: fused max-rel gather + 1x1 conv (fp16 MFMA) ----------------
// 1024 blocks x 256 threads; block = 32 nodes of one batch -> 4 blocks/CU.
// LDS: rel tile [32][192] fp16 (12 KiB, XOR-swizzled 16B granules) + sidx.
// GEMM half 1 (W cols 0..191) reads own-xs rows straight from global xt (L2-hit).
__global__ __launch_bounds__(256, 4) void k_fused(const unsigned short* __restrict__ xt,
                                                  const int* __restrict__ eidx,
                                                  const unsigned short* __restrict__ Wb,
                                                  const float* __restrict__ bias,
                                                  float* __restrict__ out) {
    __shared__ __align__(16) unsigned short rtile[32][192];   // 12 KiB
    __shared__ int sidx[32][33];                              // 4.2 KiB

    int bid  = blockIdx.x;               // 1024 blocks
    int xcd  = bid & 7;
    int b    = xcd >> 1;
    int slot = bid >> 3;                 // 0..127
    int n0   = ((xcd & 1) * 128 + slot) * 32;

    int tid  = threadIdx.x;
    int wave = tid >> 6;
    int lane = tid & 63;
    int m16  = lane & 15;
    int quad = lane >> 4;

    // ---- stage edge indices: sidx[node][0..15]=j (e0), [16..31]=i (e1) ----
    const int* e0 = eidx + ((size_t)b * N_ + n0) * K_;
    const int* e1 = e0 + (size_t)B_ * N_ * K_;
#pragma unroll
    for (int i = 0; i < 2; i++) {
        int id = i * 256 + tid;          // 0..511
        int node = id >> 4, k = id & 15;
        sidx[node][k]      = e0[id];
        sidx[node][16 + k] = e1[id];
    }

    floatx4 acc[3][2];
#pragma unroll
    for (int i = 0; i < 3; i++)
#pragma unroll
        for (int j = 0; j < 2; j++) acc[i][j] = (floatx4){0.f, 0.f, 0.f, 0.f};

    const unsigned short* wbase = Wb + (size_t)(wave * 48 + m16) * TWOC_ + quad * 8;
    const unsigned short* ybase = xt + ((size_t)b * N_ + n0 + m16) * C_ + quad * 8;

    // ---- GEMM half 1: own xs from global (no LDS dependency, overlaps sidx stage) ----
#pragma unroll 2
    for (int kt = 0; kt < 6; kt++) {
        half8 wf[3], yf[2];
#pragma unroll
        for (int i = 0; i < 3; i++)
            wf[i] = *(const half8*)(wbase + (size_t)(i * 16) * TWOC_ + kt * 32);
#pragma unroll
        for (int j = 0; j < 2; j++)
            yf[j] = *(const half8*)(ybase + (size_t)(j * 16) * C_ + kt * 32);
#pragma unroll
        for (int i = 0; i < 3; i++)
#pragma unroll
            for (int j = 0; j < 2; j++)
                acc[i][j] = __builtin_amdgcn_mfma_f32_16x16x32_f16(wf[i], yf[j], acc[i][j], 0, 0, 0);
    }

    __syncthreads();   // sidx visible to all waves

    // ---- gather max-rel (packed fp16 math) -> rtile, XOR-swizzled ----
    {
        const unsigned short* xbase = xt + (size_t)b * N_ * C_;
        int g = quad, l4 = m16;
#pragma unroll
        for (int bb = 0; bb < 2; bb++) {
            int node = wave * 8 + bb * 4 + g;
            half8  m0 = {NINF, NINF, NINF, NINF, NINF, NINF, NINF, NINF};
            half4v m1 = {NINF, NINF, NINF, NINF};
#pragma unroll
            for (int k = 0; k < K_; k++) {
                int jn  = sidx[node][k];
                int in_ = sidx[node][16 + k];
                const unsigned short* pj = xbase + (size_t)jn * C_;
                const unsigned short* pi = xbase + (size_t)in_ * C_;
                half8  a0 = *(const half8*)(pj + l4 * 8);          // ch l4*8 .. +8
                half8  b0 = *(const half8*)(pi + l4 * 8);
                half4v a1 = *(const half4v*)(pj + 128 + l4 * 4);   // ch 128+l4*4 .. +4
                half4v b1 = *(const half4v*)(pi + 128 + l4 * 4);
                m0 = __builtin_elementwise_max(m0, a0 - b0);       // v_pk_add/max_f16
                m1 = __builtin_elementwise_max(m1, a1 - b1);
            }
            char* rb = (char*)rtile + node * 384;
            unsigned int sw = (unsigned)(node & 7) << 4;
            *(half8*)(rb + ((unsigned)(l4 * 16) ^ sw))        = m0;
            *(half4v*)(rb + ((unsigned)(256 + l4 * 8) ^ sw))  = m1;
        }
    }
    __syncthreads();

    // ---- GEMM half 2: rel from LDS (swizzled reads), W cols 192..383 ----
#pragma unroll 2
    for (int kt = 0; kt < 6; kt++) {
        half8 wf[3], yf[2];
#pragma unroll
        for (int i = 0; i < 3; i++)
            wf[i] = *(const half8*)(wbase + (size_t)(i * 16) * TWOC_ + (C_ + kt * 32));
#pragma unroll
        for (int j = 0; j < 2; j++) {
            int r = j * 16 + m16;
            unsigned int off = (unsigned)(kt * 64 + quad * 16) ^ ((unsigned)(r & 7) << 4);
            yf[j] = *(const half8*)((char*)rtile + (size_t)r * 384 + off);
        }
#pragma unroll
        for (int i = 0; i < 3; i++)
#pragma unroll
            for (int j = 0; j < 2; j++)
                acc[i][j] = __builtin_amdgcn_mfma_f32_16x16x32_f16(wf[i], yf[j], acc[i][j], 0, 0, 0);
    }

    // ---- epilogue: bias + ReLU ----
#pragma unroll
    for (int i = 0; i < 3; i++) {
#pragma unroll
        for (int r = 0; r < 4; r++) {
            int o = wave * 48 + i * 16 + quad * 4 + r;
            float bv = bias[o];
#pragma unroll
            for (int j = 0; j < 2; j++) {
                int n = n0 + j * 16 + m16;
                out[((size_t)b * O_ + o) * N_ + n] = fmaxf(acc[i][j][r] + bv, 0.f);
            }
        }
    }
}

extern "C" void kernel_launch(void* const* d_in, const int* in_sizes, int n_in,
                              void* d_out, int out_size, void* d_ws, size_t ws_size,
                              hipStream_t stream) {
    const float* x    = (const float*)d_in[0];
    const int*   eidx = (const int*)d_in[2];
    const float* W    = (const float*)d_in[3];
    const float* bias = (const float*)d_in[4];
    float*       out  = (float*)d_out;

    unsigned short* Wb = (unsigned short*)d_ws;                     // 147456 B
    unsigned short* xt = (unsigned short*)((char*)d_ws + 147456);   // 12.6 MB

    k_convert_w<<<dim3((O_ * TWOC_ + 255) / 256), dim3(256), 0, stream>>>(W, Wb);
    k_transpose<<<dim3(6144), dim3(256), 0, stream>>>(x, xt);
    k_fused<<<dim3(1024), dim3(256), 0, stream>>>(xt, eidx, Wb, bias, out);
}

// Round 2
// 135.948 us; speedup vs baseline: 1.0247x; 1.0247x over previous
//
#include <hip/hip_runtime.h>
#include <hip/hip_fp16.h>

#define B_    4
#define C_    192
#define N_    8192
#define K_    16
#define O_    192
#define TWOC_ 384
#define BN_   (B_ * N_)

typedef __attribute__((ext_vector_type(8))) _Float16 half8;
typedef __attribute__((ext_vector_type(4))) _Float16 half4v;
typedef __attribute__((ext_vector_type(4))) float floatx4;

static __device__ __forceinline__ half8 shflx8(half8 v, int m) {
    union { half8 h; int i[4]; } u;
    u.h = v;
#pragma unroll
    for (int q = 0; q < 4; q++) u.i[q] = __shfl_xor(u.i[q], m, 64);
    return u.h;
}
static __device__ __forceinline__ half4v shflx4(half4v v, int m) {
    union { half4v h; int i[2]; } u;
    u.h = v;
#pragma unroll
    for (int q = 0; q < 2; q++) u.i[q] = __shfl_xor(u.i[q], m, 64);
    return u.h;
}

// ---------------- K0: W fp32 -> fp16 ----------------
__global__ __launch_bounds__(256) void k_convert_w(const float* __restrict__ W,
                                                   unsigned short* __restrict__ Wb) {
    int i = blockIdx.x * 256 + threadIdx.x;
    if (i < O_ * TWOC_) {
        union { _Float16 h; unsigned short s; } v;
        v.h = (_Float16)W[i];
        Wb[i] = v.s;
    }
}

// ---------------- K1: x[B,C,N] fp32 -> xt[B,N,192] fp16 (compact) ----------------
__global__ __launch_bounds__(256) void k_transpose(const float* __restrict__ x,
                                                   unsigned short* __restrict__ xt) {
    __shared__ float tile[32][33];
    int bid  = blockIdx.x;               // 6144 blocks
    int xcd  = bid & 7;
    int b    = xcd >> 1;
    int half = xcd & 1;
    int slot = bid >> 3;                 // 0..767
    int ct   = slot >> 7;                // 0..5
    int nt   = half * 128 + (slot & 127);// 0..255
    int c0 = ct * 32, n0 = nt * 32;
    int tid = threadIdx.x;

    int cc  = tid >> 3;                  // 0..31
    int nn4 = (tid & 7) * 4;             // 0,4,..,28
    const float* xp = x + ((size_t)b * C_ + c0 + cc) * N_ + n0 + nn4;
    float4 v = *(const float4*)xp;
    tile[nn4 + 0][cc] = v.x;
    tile[nn4 + 1][cc] = v.y;
    tile[nn4 + 2][cc] = v.z;
    tile[nn4 + 3][cc] = v.w;
    __syncthreads();

#pragma unroll
    for (int i = 0; i < 2; i++) {
        int id  = i * 256 + tid;         // 0..511
        int row = id >> 4;               // 0..31
        int ch2 = id & 15;               // 0..15
        union { _Float16 h[2]; unsigned int u; } p;
        p.h[0] = (_Float16)tile[row][ch2 * 2];
        p.h[1] = (_Float16)tile[row][ch2 * 2 + 1];
        *(unsigned int*)(xt + ((size_t)b * N_ + n0 + row) * C_ + c0 + ch2 * 2) = p.u;
    }
}

// ---------------- KG: max-rel gather, high-MLP, no GEMM ----------------
// 2048 blocks x 4 waves; wave = 4 nodes. lane: part = lane&15 (12 ch),
// kg = lane>>4 (4 of the 16 k's, reduced serially in-register, then
// butterfly shfl_xor 16/32 across kg). All 16 row-pair loads per node
// are mutually independent -> max memory-level parallelism.
__global__ __launch_bounds__(256) void k_gather(const unsigned short* __restrict__ xt,
                                                const int* __restrict__ eidx,
                                                unsigned short* __restrict__ rt) {
    int tid  = threadIdx.x;
    int lane = tid & 63;
    int w    = tid >> 6;
    int part = lane & 15;
    int kg   = lane >> 4;

    int bid  = blockIdx.x;               // 2048
    int xcd  = bid & 7;
    int b    = xcd >> 1;
    int half = xcd & 1;
    int slot = bid >> 3;                 // 0..255
    int widx = slot * 4 + w;             // 0..1023
    int nbase = half * 4096 + widx * 4;

    const unsigned short* xb = xt + (size_t)b * N_ * C_;
    const int* e0 = eidx + ((size_t)b * N_ + nbase) * K_;
    const int* e1 = e0 + (size_t)BN_ * K_;

#pragma unroll
    for (int nn = 0; nn < 4; nn++) {
        int4 j4 = *(const int4*)(e0 + nn * K_ + kg * 4);
        int4 i4 = *(const int4*)(e1 + nn * K_ + kg * 4);
        half8  m0;
        half4v m1;
#pragma unroll
        for (int it = 0; it < 4; it++) {
            int jn  = (it == 0) ? j4.x : (it == 1) ? j4.y : (it == 2) ? j4.z : j4.w;
            int in_ = (it == 0) ? i4.x : (it == 1) ? i4.y : (it == 2) ? i4.z : i4.w;
            const unsigned short* pj = xb + (size_t)jn * C_;
            const unsigned short* pi = xb + (size_t)in_ * C_;
            half8  a0 = *(const half8*)(pj + part * 8);          // ch part*8 .. +8
            half4v a1 = *(const half4v*)(pj + 128 + part * 4);   // ch 128+part*4 .. +4
            half8  b0 = *(const half8*)(pi + part * 8);
            half4v b1 = *(const half4v*)(pi + 128 + part * 4);
            half8  d0 = a0 - b0;
            half4v d1 = a1 - b1;
            if (it == 0) { m0 = d0; m1 = d1; }
            else {
                m0 = __builtin_elementwise_max(m0, d0);
                m1 = __builtin_elementwise_max(m1, d1);
            }
        }
        // reduce across kg (lane bits 4,5)
        m0 = __builtin_elementwise_max(m0, shflx8(m0, 16));
        m1 = __builtin_elementwise_max(m1, shflx4(m1, 16));
        m0 = __builtin_elementwise_max(m0, shflx8(m0, 32));
        m1 = __builtin_elementwise_max(m1, shflx4(m1, 32));

        if (kg == 0) {
            unsigned short* ro = rt + ((size_t)b * N_ + nbase + nn) * C_;
            *(half8*)(ro + part * 8)        = m0;
            *(half4v*)(ro + 128 + part * 4) = m1;
        }
    }
}

// ---------------- KC: 1x1 conv GEMM (fp16 MFMA), swizzled LDS y-tile ----------------
// 512 blocks x 4 waves; block = 64 nodes. ytile[64][384] fp16 (48 KiB),
// XOR-swizzle byte^((row&7)<<4) kills the stride-768 bank conflicts.
__global__ __launch_bounds__(256) void k_conv(const unsigned short* __restrict__ xt,
                                              const unsigned short* __restrict__ rt,
                                              const unsigned short* __restrict__ Wb,
                                              const float* __restrict__ bias,
                                              float* __restrict__ out) {
    __shared__ __align__(16) unsigned short ytile[64 * TWOC_];   // 48 KiB
    char* yb = (char*)ytile;

    int bid  = blockIdx.x;               // 512
    int xcd  = bid & 7;
    int b    = xcd >> 1;
    int slot = bid >> 3;                 // 0..63
    int n0   = ((xcd & 1) * 64 + slot) * 64;

    int tid  = threadIdx.x;
    int wave = tid >> 6;
    int lane = tid & 63;
    int m16  = lane & 15;
    int quad = lane >> 4;

    // ---- stage y = [xs | rel] into swizzled LDS ----
    const unsigned short* xsrc = xt + ((size_t)b * N_ + n0) * C_;
    const unsigned short* rsrc = rt + ((size_t)b * N_ + n0) * C_;
#pragma unroll
    for (int i = 0; i < 6; i++) {
        int id = i * 256 + tid;          // 0..1535
        int row = id / 24, chunk = id % 24;
        int sw = (row & 7) << 4;
        half8 vx = *(const half8*)(xsrc + (size_t)row * C_ + chunk * 8);
        half8 vr = *(const half8*)(rsrc + (size_t)row * C_ + chunk * 8);
        *(half8*)(yb + row * 768 + ((chunk * 16) ^ sw))       = vx;
        *(half8*)(yb + row * 768 + 384 + ((chunk * 16) ^ sw)) = vr;
    }
    __syncthreads();

    // ---- GEMM: wave w covers o rows [w*48, w*48+48), all 64 n ----
    const unsigned short* wbase = Wb + (size_t)(wave * 48 + m16) * TWOC_ + quad * 8;

    floatx4 acc[3][4];
#pragma unroll
    for (int i = 0; i < 3; i++)
#pragma unroll
        for (int j = 0; j < 4; j++) acc[i][j] = (floatx4){0.f, 0.f, 0.f, 0.f};

#pragma unroll 2
    for (int kt = 0; kt < 12; kt++) {
        half8 wf[3], yf[4];
#pragma unroll
        for (int i = 0; i < 3; i++)
            wf[i] = *(const half8*)(wbase + (size_t)(i * 16) * TWOC_ + kt * 32);
#pragma unroll
        for (int j = 0; j < 4; j++) {
            int row = j * 16 + m16;
            yf[j] = *(const half8*)(yb + row * 768 + ((kt * 64 + quad * 16) ^ ((row & 7) << 4)));
        }
#pragma unroll
        for (int i = 0; i < 3; i++)
#pragma unroll
            for (int j = 0; j < 4; j++)
                acc[i][j] = __builtin_amdgcn_mfma_f32_16x16x32_f16(wf[i], yf[j], acc[i][j], 0, 0, 0);
    }

    // ---- epilogue: bias + ReLU ----
#pragma unroll
    for (int i = 0; i < 3; i++) {
#pragma unroll
        for (int r = 0; r < 4; r++) {
            int o = wave * 48 + i * 16 + quad * 4 + r;
            float bv = bias[o];
#pragma unroll
            for (int j = 0; j < 4; j++) {
                int n = n0 + j * 16 + m16;
                out[((size_t)b * O_ + o) * N_ + n] = fmaxf(acc[i][j][r] + bv, 0.f);
            }
        }
    }
}

extern "C" void kernel_launch(void* const* d_in, const int* in_sizes, int n_in,
                              void* d_out, int out_size, void* d_ws, size_t ws_size,
                              hipStream_t stream) {
    const float* x    = (const float*)d_in[0];
    const int*   eidx = (const int*)d_in[2];
    const float* W    = (const float*)d_in[3];
    const float* bias = (const float*)d_in[4];
    float*       out  = (float*)d_out;

    unsigned short* Wb = (unsigned short*)d_ws;                       // 147456 B
    unsigned short* xt = (unsigned short*)((char*)d_ws + 147456);     // 12.58 MB
    unsigned short* rt = (unsigned short*)((char*)d_ws + 12730368);   // 12.58 MB

    k_convert_w<<<dim3((O_ * TWOC_ + 255) / 256), dim3(256), 0, stream>>>(W, Wb);
    k_transpose<<<dim3(6144), dim3(256), 0, stream>>>(x, xt);
    k_gather<<<dim3(2048), dim3(256), 0, stream>>>(xt, eidx, rt);
    k_conv<<<dim3(512), dim3(256), 0, stream>>>(xt, rt, Wb, bias, out);
}